// Round 3
// baseline (836.808 us; speedup 1.0000x reference)
//
#include <hip/hip_runtime.h>
#include <hip/hip_bf16.h>
#include <math.h>
#include <stdint.h>

typedef __bf16 bf16;
typedef __bf16 bf16x8 __attribute__((ext_vector_type(8)));
typedef float  floatx4 __attribute__((ext_vector_type(4)));

#define HEADS 8
#define DH    64
#define NB    8
#define NTOK  4096
#define CDIM  512
#define MTOT  32768
#define PART_STRIDE 16777216L   // elements: 32768*512

__global__ void detect_kernel(const bf16* __restrict__ w, int* __restrict__ flag)
{
    __shared__ int cnt[256];
    int c = 0;
    for (int i = 0; i < 64; ++i) {
        float v = fabsf((float)w[threadIdx.x + i * 256]);
        if (v > 1e3f) c++;
    }
    cnt[threadIdx.x] = c;
    __syncthreads();
    if (threadIdx.x == 0) {
        int s = 0;
        for (int i = 0; i < 256; ++i) s += cnt[i];
        *flag = (s > 500) ? 1 : 0;   // 1 => inputs are fp32
    }
}

// misc floats: [0..7] temp0, [8..15] temp1, [16..527] bias0, [528..1039] bias1
__global__ void misc_kernel(const void* t0, const void* t1, const void* b0, const void* b1,
                            const int* __restrict__ flag, float* __restrict__ misc)
{
    bool f32 = (*flag != 0);
    int tid = threadIdx.x;
    #define RD(p, i) (f32 ? ((const float*)(p))[i] : (float)((const bf16*)(p))[i])
    if (tid < 8) { misc[tid] = RD(t0, tid); misc[8 + tid] = RD(t1, tid); }
    for (int i = tid; i < 512; i += 256) {
        misc[16 + i]  = RD(b0, i);
        misc[528 + i] = RD(b1, i);
    }
    #undef RD
}

__global__ void wt_kernel(const void* __restrict__ W, bf16* __restrict__ Wt, int K, int N,
                          const int* __restrict__ flag)
{
    int idx = blockIdx.x * 256 + threadIdx.x;
    if (idx >= K * N) return;
    bool f32 = (*flag != 0);
    int n = idx / K;
    int k = idx - n * K;
    float v = f32 ? ((const float*)W)[k * N + n] : (float)((const bf16*)W)[k * N + n];
    Wt[idx] = (bf16)v;
}

// C = A[M][K] * Bt[N][K]^T (+bias). A: bf16 or fp32 (aflag). part = col>>9:
// parts 0/1 -> C at c_base + part*PART_STRIDE (fp32 if cflag else bf16), part 2 -> Cv (bf16).
#define BK 64
__global__ __launch_bounds__(256) void gemm_bt(
    const void* __restrict__ A, const bf16* __restrict__ Bt,
    const float* __restrict__ bias, void* __restrict__ C, bf16* __restrict__ Cv,
    int M, int N, int K, long c_base,
    const int* __restrict__ aflag, const int* __restrict__ cflag)
{
    __shared__ bf16 As[128][BK + 8];
    __shared__ bf16 Bs[128][BK + 8];

    bool af32 = aflag && (*aflag != 0);
    bool cf32 = cflag && (*cflag != 0);

    int tid  = threadIdx.x;
    int lane = tid & 63;
    int wave = tid >> 6;
    int wm   = (wave >> 1) * 64;
    int wn   = (wave & 1) * 64;
    int l15  = lane & 15;
    int quad = lane >> 4;

    int m0 = blockIdx.y * 128;
    int n0 = blockIdx.x * 128;

    floatx4 acc[4][4] = {};

    int sr = tid >> 3;
    int sc = (tid & 7) * 8;

    for (int k0 = 0; k0 < K; k0 += BK) {
        #pragma unroll
        for (int p = 0; p < 4; ++p) {
            int row = p * 32 + sr;
            if (af32) {
                const float* Af = (const float*)A + (size_t)(m0 + row) * K + k0 + sc;
                float4 f0 = *(const float4*)Af;
                float4 f1 = *(const float4*)(Af + 4);
                bf16 t[8] = {(bf16)f0.x, (bf16)f0.y, (bf16)f0.z, (bf16)f0.w,
                             (bf16)f1.x, (bf16)f1.y, (bf16)f1.z, (bf16)f1.w};
                *(uint4*)&As[row][sc] = *(uint4*)t;
            } else {
                *(uint4*)&As[row][sc] =
                    *(const uint4*)((const bf16*)A + (size_t)(m0 + row) * K + k0 + sc);
            }
            *(uint4*)&Bs[row][sc] = *(const uint4*)&Bt[(size_t)(n0 + row) * K + k0 + sc];
        }
        __syncthreads();
        #pragma unroll
        for (int ks = 0; ks < BK; ks += 32) {
            bf16x8 af[4], bfr[4];
            #pragma unroll
            for (int i = 0; i < 4; ++i)
                af[i] = *(bf16x8*)&As[wm + i * 16 + l15][ks + quad * 8];
            #pragma unroll
            for (int j = 0; j < 4; ++j)
                bfr[j] = *(bf16x8*)&Bs[wn + j * 16 + l15][ks + quad * 8];
            #pragma unroll
            for (int i = 0; i < 4; ++i)
                #pragma unroll
                for (int j = 0; j < 4; ++j)
                    acc[i][j] = __builtin_amdgcn_mfma_f32_16x16x32_bf16(af[i], bfr[j], acc[i][j], 0, 0, 0);
        }
        __syncthreads();
    }

    #pragma unroll
    for (int j = 0; j < 4; ++j) {
        int col  = n0 + wn + j * 16 + l15;
        int part = col >> 9;
        int cw   = col & 511;
        float bv = bias ? bias[col] : 0.0f;
        #pragma unroll
        for (int i = 0; i < 4; ++i) {
            int row = m0 + wm + i * 16 + quad * 4;
            #pragma unroll
            for (int rr = 0; rr < 4; ++rr) {
                float v = acc[i][j][rr] + bv;
                long idx = (long)(row + rr) * CDIM + cw;
                if (part == 2)      Cv[idx] = (bf16)v;
                else if (cf32)      ((float*)C)[c_base + part * PART_STRIDE + idx] = v;
                else                ((bf16*)C)[c_base + part * PART_STRIDE + idx] = (bf16)v;
            }
        }
    }
}

__device__ inline void unpack8(uint4 u, float* dst) {
    uint32_t w[4] = {u.x, u.y, u.z, u.w};
    #pragma unroll
    for (int i = 0; i < 4; ++i) {
        dst[2 * i]     = __uint_as_float(w[i] << 16);
        dst[2 * i + 1] = __uint_as_float(w[i] & 0xffff0000u);
    }
}

__global__ __launch_bounds__(256) void xca_gk(
    const bf16* __restrict__ Q0, const bf16* __restrict__ K0,
    const bf16* __restrict__ Q1, const bf16* __restrict__ K1,
    float* __restrict__ G, float* __restrict__ NQ, float* __restrict__ NK)
{
    __shared__ float qc[64][68];
    __shared__ float kc[64][68];

    int bid = blockIdx.x;
    int nq4 = bid & 3;
    int h   = (bid >> 2) & 7;
    int b   = (bid >> 5) & 7;
    int s   = bid >> 8;
    int sbh = s * 64 + b * 8 + h;

    const bf16* qsrc = s ? Q1 : Q0;
    const bf16* ksrc = s ? K0 : K1;

    int tid  = threadIdx.x;
    int nloc = tid >> 2;
    int d8   = (tid & 3) * 8;
    int d0   = (tid >> 4) * 4;
    int e0   = (tid & 15) * 4;

    float acc[4][4] = {};
    float nacc = 0.f;

    int n_start = nq4 * 1024;
    for (int ch = 0; ch < 16; ++ch) {
        int ng = n_start + ch * 64 + nloc;
        const bf16* qp = qsrc + (long)(b * NTOK + ng) * CDIM + h * DH;
        const bf16* kp = ksrc + (long)(b * NTOK + ng) * CDIM + h * DH;
        uint4 qA = *(const uint4*)(qp + d8);
        uint4 qB = *(const uint4*)(qp + 32 + d8);
        uint4 kA = *(const uint4*)(kp + d8);
        uint4 kB = *(const uint4*)(kp + 32 + d8);
        __syncthreads();
        unpack8(qA, &qc[nloc][d8]);
        unpack8(qB, &qc[nloc][32 + d8]);
        unpack8(kA, &kc[nloc][d8]);
        unpack8(kB, &kc[nloc][32 + d8]);
        __syncthreads();

        if (tid < 64) {
            #pragma unroll 8
            for (int n = 0; n < 64; ++n) { float v = qc[n][tid]; nacc += v * v; }
        } else if (tid < 128) {
            int dd = tid - 64;
            #pragma unroll 8
            for (int n = 0; n < 64; ++n) { float v = kc[n][dd]; nacc += v * v; }
        }
        #pragma unroll 4
        for (int n = 0; n < 64; ++n) {
            floatx4 qd = *(floatx4*)&qc[n][d0];
            floatx4 ke = *(floatx4*)&kc[n][e0];
            #pragma unroll
            for (int i = 0; i < 4; ++i)
                #pragma unroll
                for (int j = 0; j < 4; ++j)
                    acc[i][j] += qd[i] * ke[j];
        }
    }
    float* Gp = G + (sbh * 64 + d0) * 64 + e0;
    #pragma unroll
    for (int i = 0; i < 4; ++i)
        #pragma unroll
        for (int j = 0; j < 4; ++j)
            atomicAdd(&Gp[i * 64 + j], acc[i][j]);
    if (tid < 64)       atomicAdd(&NQ[sbh * 64 + tid], nacc);
    else if (tid < 128) atomicAdd(&NK[sbh * 64 + tid - 64], nacc);
}

__global__ void xca_soft(const float* __restrict__ G,
                         const float* __restrict__ NQ, const float* __restrict__ NK,
                         const float* __restrict__ misc, bf16* __restrict__ P)
{
    int sbh = blockIdx.x;
    int s = sbh >> 6;
    int h = sbh & 7;
    int d = threadIdx.x;

    __shared__ float rk[64];
    rk[d] = 1.0f / fmaxf(sqrtf(NK[sbh * 64 + d]), 1e-12f);
    __syncthreads();

    float rq = 1.0f / fmaxf(sqrtf(NQ[sbh * 64 + d]), 1e-12f);
    float t  = misc[s * 8 + h];
    const float* Gr = G + (sbh * 64 + d) * 64;

    float a[64];
    float mx = -1e30f;
    #pragma unroll
    for (int e = 0; e < 64; ++e) {
        a[e] = Gr[e] * rq * rk[e] * t;
        mx = fmaxf(mx, a[e]);
    }
    float sum = 0.f;
    #pragma unroll
    for (int e = 0; e < 64; ++e) { a[e] = expf(a[e] - mx); sum += a[e]; }
    float inv = 1.0f / sum;
    bf16* Pr = P + (sbh * 64 + d) * 64;
    #pragma unroll
    for (int e = 0; e < 64; ++e) Pr[e] = (bf16)(a[e] * inv);
}

__global__ __launch_bounds__(256) void xca_pv(
    const bf16* __restrict__ V0, const bf16* __restrict__ V1,
    const bf16* __restrict__ P, bf16* __restrict__ xca)
{
    int bid = blockIdx.x;
    int nq4 = bid & 3;
    int h   = (bid >> 2) & 7;
    int b   = (bid >> 5) & 7;
    int s   = bid >> 8;
    int sbh = s * 64 + b * 8 + h;

    const bf16* vsrc = s ? V0 : V1;

    int tid = threadIdx.x;
    int lane = tid & 63;
    int wave = tid >> 6;
    int l15 = lane & 15;
    int quad = lane >> 4;

    const bf16* Pb = P + sbh * 4096;
    bf16x8 pf[4][2];
    #pragma unroll
    for (int i = 0; i < 4; ++i)
        #pragma unroll
        for (int h2 = 0; h2 < 2; ++h2)
            pf[i][h2] = *(const bf16x8*)&Pb[(i * 16 + l15) * 64 + h2 * 32 + quad * 8];

    int n_start = nq4 * 1024 + wave * 256;
    for (int nt = 0; nt < 16; ++nt) {
        int nb = n_start + nt * 16;
        const bf16* vp = vsrc + (long)(b * NTOK + nb + l15) * CDIM + h * DH + quad * 8;
        bf16x8 v0 = *(const bf16x8*)vp;
        bf16x8 v1 = *(const bf16x8*)(vp + 32);
        floatx4 acc[4] = {};
        #pragma unroll
        for (int i = 0; i < 4; ++i) {
            acc[i] = __builtin_amdgcn_mfma_f32_16x16x32_bf16(v0, pf[i][0], acc[i], 0, 0, 0);
            acc[i] = __builtin_amdgcn_mfma_f32_16x16x32_bf16(v1, pf[i][1], acc[i], 0, 0, 0);
        }
        bf16* op = xca + (long)((s * NB + b) * NTOK + nb + quad * 4) * CDIM + h * DH + l15;
        #pragma unroll
        for (int i = 0; i < 4; ++i)
            #pragma unroll
            for (int r = 0; r < 4; ++r)
                op[(long)r * CDIM + i * 16] = (bf16)acc[i][r];
    }
}

extern "C" void kernel_launch(void* const* d_in, const int* in_sizes, int n_in,
                              void* d_out, int out_size, void* d_ws, size_t ws_size,
                              hipStream_t stream)
{
    const void* x     = d_in[0];
    const void* x_d   = d_in[1];
    const void* Wq0   = d_in[2];
    const void* Wq1   = d_in[3];
    const void* temp0 = d_in[4];
    const void* temp1 = d_in[5];
    const void* Wp0   = d_in[6];
    const void* bp0   = d_in[7];
    const void* Wp1   = d_in[8];
    const void* bp1   = d_in[9];

    char* ws = (char*)d_ws;
    bf16*  Q0   = (bf16*)(ws);
    bf16*  K0   = (bf16*)(ws + 33554432);
    bf16*  Q1   = (bf16*)(ws + 67108864);
    bf16*  K1   = (bf16*)(ws + 100663296);
    bf16*  xca  = (bf16*)(ws);             // overlay on Q0+K0 (dead after xca_gk)
    bf16*  wtq0 = (bf16*)(ws + 134217728);
    bf16*  wtq1 = (bf16*)(ws + 135790592);
    bf16*  wtp0 = (bf16*)(ws + 137363456);
    bf16*  wtp1 = (bf16*)(ws + 137887744);
    float* G    = (float*)(ws + 138412032);
    float* NQ   = (float*)(ws + 140509184);
    float* NK   = (float*)(ws + 140541952);
    bf16*  P    = (bf16*)(ws + 140574720);
    int*   flag = (int*)(ws + 141623296);
    float* misc = (float*)(ws + 141623360);

    bf16* V0 = (bf16*)d_out;               // V scratch in d_out (always bf16)
    bf16* V1 = (bf16*)d_out + PART_STRIDE;

    hipMemsetAsync(ws + 138412032, 0, 2162688, stream);   // zero G + NQ + NK

    detect_kernel<<<1, 256, 0, stream>>>((const bf16*)Wq0, flag);
    misc_kernel<<<1, 256, 0, stream>>>(temp0, temp1, bp0, bp1, flag, misc);

    wt_kernel<<<(512 * 1536 + 255) / 256, 256, 0, stream>>>(Wq0, wtq0, 512, 1536, flag);
    wt_kernel<<<(512 * 1536 + 255) / 256, 256, 0, stream>>>(Wq1, wtq1, 512, 1536, flag);
    wt_kernel<<<(512 * 512 + 255) / 256, 256, 0, stream>>>(Wp0, wtp0, 512, 512, flag);
    wt_kernel<<<(512 * 512 + 255) / 256, 256, 0, stream>>>(Wp1, wtp1, 512, 512, flag);

    // QKV: parts 0/1 -> Q,K in ws (c_base=0); part 2 -> V scratch in d_out
    gemm_bt<<<dim3(12, 256), 256, 0, stream>>>(
        x,   wtq0, nullptr, Q0, V0, MTOT, 1536, 512, 0L, flag, nullptr);
    gemm_bt<<<dim3(12, 256), 256, 0, stream>>>(
        x_d, wtq1, nullptr, Q1, V1, MTOT, 1536, 512, 0L, flag, nullptr);

    xca_gk<<<512, 256, 0, stream>>>(Q0, K0, Q1, K1, G, NQ, NK);
    xca_soft<<<128, 64, 0, stream>>>(G, NQ, NK, misc, P);
    xca_pv<<<512, 256, 0, stream>>>(V0, V1, P, xca);

    // proj GEMMs: A = xca (bf16), out dtype per flag; 2nd half at element offset PART_STRIDE
    gemm_bt<<<dim3(4, 256), 256, 0, stream>>>(
        xca,               wtp0, misc + 16,  d_out, nullptr, MTOT, 512, 512, 0L,          nullptr, flag);
    gemm_bt<<<dim3(4, 256), 256, 0, stream>>>(
        xca + PART_STRIDE, wtp1, misc + 528, d_out, nullptr, MTOT, 512, 512, PART_STRIDE, nullptr, flag);
}

// Round 4
// 732.186 us; speedup vs baseline: 1.1429x; 1.1429x over previous
//
#include <hip/hip_runtime.h>
#include <hip/hip_bf16.h>
#include <math.h>
#include <stdint.h>

typedef __bf16 bf16;
typedef __bf16 bf16x8 __attribute__((ext_vector_type(8)));
typedef float  floatx4 __attribute__((ext_vector_type(4)));

#define HEADS 8
#define DH    64
#define NB    8
#define NTOK  4096
#define CDIM  512
#define MTOT  32768
#define PART_STRIDE 16777216L   // elements: 32768*512

// async global->LDS, 16B per lane; LDS dst = wave-uniform base + lane*16 (m97/m104)
__device__ __forceinline__ void gload16(const bf16* g, bf16* l) {
    __builtin_amdgcn_global_load_lds(
        (const __attribute__((address_space(1))) unsigned int*)g,
        (__attribute__((address_space(3))) unsigned int*)l,
        16, 0, 0);
}

__global__ void detect_kernel(const bf16* __restrict__ w, int* __restrict__ flag)
{
    __shared__ int cnt[256];
    int c = 0;
    for (int i = 0; i < 64; ++i) {
        float v = fabsf((float)w[threadIdx.x + i * 256]);
        if (v > 1e3f) c++;
    }
    cnt[threadIdx.x] = c;
    __syncthreads();
    if (threadIdx.x == 0) {
        int s = 0;
        for (int i = 0; i < 256; ++i) s += cnt[i];
        *flag = (s > 500) ? 1 : 0;   // 1 => inputs are fp32
    }
}

// misc floats: [0..7] temp0, [8..15] temp1, [16..527] bias0, [528..1039] bias1
__global__ void misc_kernel(const void* t0, const void* t1, const void* b0, const void* b1,
                            const int* __restrict__ flag, float* __restrict__ misc)
{
    bool f32 = (*flag != 0);
    int tid = threadIdx.x;
    #define RD(p, i) (f32 ? ((const float*)(p))[i] : (float)((const bf16*)(p))[i])
    if (tid < 8) { misc[tid] = RD(t0, tid); misc[8 + tid] = RD(t1, tid); }
    for (int i = tid; i < 512; i += 256) {
        misc[16 + i]  = RD(b0, i);
        misc[528 + i] = RD(b1, i);
    }
    #undef RD
}

__global__ void wt_kernel(const void* __restrict__ W, bf16* __restrict__ Wt, int K, int N,
                          const int* __restrict__ flag)
{
    int idx = blockIdx.x * 256 + threadIdx.x;
    if (idx >= K * N) return;
    bool f32 = (*flag != 0);
    int n = idx / K;
    int k = idx - n * K;
    float v = f32 ? ((const float*)W)[k * N + n] : (float)((const bf16*)W)[k * N + n];
    Wt[idx] = (bf16)v;
}

// X (fp32 or bf16 per flag) -> Y bf16; 8 elements/thread, 16,777,216 elements
__global__ void cast_kernel(const void* __restrict__ X, bf16* __restrict__ Y,
                            const int* __restrict__ flag)
{
    size_t i = ((size_t)blockIdx.x * 256 + threadIdx.x) * 8;
    if (*flag) {
        const float* xf = (const float*)X + i;
        float4 a = *(const float4*)xf;
        float4 b = *(const float4*)(xf + 4);
        bf16 t[8] = {(bf16)a.x, (bf16)a.y, (bf16)a.z, (bf16)a.w,
                     (bf16)b.x, (bf16)b.y, (bf16)b.z, (bf16)b.w};
        *(uint4*)(Y + i) = *(uint4*)t;
    } else {
        *(uint4*)(Y + i) = *(const uint4*)((const bf16*)X + i);
    }
}

// C = A[M][512] * Bt[N][512]^T (+bias). All bf16 in; K=512 fixed.
// grid: x = m-blocks (fastest -> A streamed once per y-pass, L3-resident),
//       y = n-blocks. 128x128 tile, 4 waves 2x2, BK=64, unpadded LDS (global_load_lds).
// part = col>>9: parts 0/1 -> C at c_base+part*PART_STRIDE (fp32 if cflag else bf16),
// part 2 -> Cv (bf16).
__global__ __launch_bounds__(256) void gemm_bt(
    const bf16* __restrict__ A, const bf16* __restrict__ Bt,
    const float* __restrict__ bias, void* __restrict__ C, bf16* __restrict__ Cv,
    long c_base, const int* __restrict__ cflag)
{
    __shared__ bf16 As[128 * 64];
    __shared__ bf16 Bs[128 * 64];

    bool cf32 = cflag && (*cflag != 0);

    int tid  = threadIdx.x;
    int lane = tid & 63;
    int w    = tid >> 6;
    int wm   = (w >> 1) * 64;
    int wn   = (w & 1) * 64;
    int l15  = lane & 15;
    int quad = lane >> 4;

    int m0 = blockIdx.x * 128;
    int n0 = blockIdx.y * 128;

    // staging addresses: wave w covers rows [w*32, w*32+32), 8 rows per gload16
    const bf16* Ab = A  + (size_t)(m0 + w * 32 + (lane >> 3)) * 512 + (lane & 7) * 8;
    const bf16* Bb = Bt + (size_t)(n0 + w * 32 + (lane >> 3)) * 512 + (lane & 7) * 8;
    bf16* Asw = &As[(w * 32) * 64];
    bf16* Bsw = &Bs[(w * 32) * 64];

    floatx4 acc[4][4] = {};

    for (int k0 = 0; k0 < 512; k0 += 64) {
        #pragma unroll
        for (int i = 0; i < 4; ++i) {
            gload16(Ab + k0 + i * 8 * 512, Asw + i * 8 * 64);
            gload16(Bb + k0 + i * 8 * 512, Bsw + i * 8 * 64);
        }
        __syncthreads();
        #pragma unroll
        for (int ks = 0; ks < 64; ks += 32) {
            bf16x8 af[4], bfr[4];
            #pragma unroll
            for (int i = 0; i < 4; ++i)
                af[i] = *(bf16x8*)&As[(wm + i * 16 + l15) * 64 + ks + quad * 8];
            #pragma unroll
            for (int j = 0; j < 4; ++j)
                bfr[j] = *(bf16x8*)&Bs[(wn + j * 16 + l15) * 64 + ks + quad * 8];
            #pragma unroll
            for (int i = 0; i < 4; ++i)
                #pragma unroll
                for (int j = 0; j < 4; ++j)
                    acc[i][j] = __builtin_amdgcn_mfma_f32_16x16x32_bf16(af[i], bfr[j], acc[i][j], 0, 0, 0);
        }
        __syncthreads();
    }

    // D layout: col = lane&15, row = quad*4 + reg (verified m89/m91)
    #pragma unroll
    for (int j = 0; j < 4; ++j) {
        int col  = n0 + wn + j * 16 + l15;
        int part = col >> 9;
        int cw   = col & 511;
        float bv = bias ? bias[col] : 0.0f;
        #pragma unroll
        for (int i = 0; i < 4; ++i) {
            int row = m0 + wm + i * 16 + quad * 4;
            #pragma unroll
            for (int rr = 0; rr < 4; ++rr) {
                float v = acc[i][j][rr] + bv;
                long idx = (long)(row + rr) * CDIM + cw;
                if (part == 2)      Cv[idx] = (bf16)v;
                else if (cf32)      ((float*)C)[c_base + part * PART_STRIDE + idx] = v;
                else                ((bf16*)C)[c_base + part * PART_STRIDE + idx] = (bf16)v;
            }
        }
    }
}

__device__ inline void unpack8(uint4 u, float* dst) {
    uint32_t w[4] = {u.x, u.y, u.z, u.w};
    #pragma unroll
    for (int i = 0; i < 4; ++i) {
        dst[2 * i]     = __uint_as_float(w[i] << 16);
        dst[2 * i + 1] = __uint_as_float(w[i] & 0xffff0000u);
    }
}

__global__ __launch_bounds__(256) void xca_gk(
    const bf16* __restrict__ Q0, const bf16* __restrict__ K0,
    const bf16* __restrict__ Q1, const bf16* __restrict__ K1,
    float* __restrict__ G, float* __restrict__ NQ, float* __restrict__ NK)
{
    __shared__ float qc[64][68];
    __shared__ float kc[64][68];

    int bid = blockIdx.x;
    int nq4 = bid & 3;
    int h   = (bid >> 2) & 7;
    int b   = (bid >> 5) & 7;
    int s   = bid >> 8;
    int sbh = s * 64 + b * 8 + h;

    const bf16* qsrc = s ? Q1 : Q0;
    const bf16* ksrc = s ? K0 : K1;

    int tid  = threadIdx.x;
    int nloc = tid >> 2;
    int d8   = (tid & 3) * 8;
    int d0   = (tid >> 4) * 4;
    int e0   = (tid & 15) * 4;

    float acc[4][4] = {};
    float nacc = 0.f;

    int n_start = nq4 * 1024;
    for (int ch = 0; ch < 16; ++ch) {
        int ng = n_start + ch * 64 + nloc;
        const bf16* qp = qsrc + (long)(b * NTOK + ng) * CDIM + h * DH;
        const bf16* kp = ksrc + (long)(b * NTOK + ng) * CDIM + h * DH;
        uint4 qA = *(const uint4*)(qp + d8);
        uint4 qB = *(const uint4*)(qp + 32 + d8);
        uint4 kA = *(const uint4*)(kp + d8);
        uint4 kB = *(const uint4*)(kp + 32 + d8);
        __syncthreads();
        unpack8(qA, &qc[nloc][d8]);
        unpack8(qB, &qc[nloc][32 + d8]);
        unpack8(kA, &kc[nloc][d8]);
        unpack8(kB, &kc[nloc][32 + d8]);
        __syncthreads();

        if (tid < 64) {
            #pragma unroll 8
            for (int n = 0; n < 64; ++n) { float v = qc[n][tid]; nacc += v * v; }
        } else if (tid < 128) {
            int dd = tid - 64;
            #pragma unroll 8
            for (int n = 0; n < 64; ++n) { float v = kc[n][dd]; nacc += v * v; }
        }
        #pragma unroll 4
        for (int n = 0; n < 64; ++n) {
            floatx4 qd = *(floatx4*)&qc[n][d0];
            floatx4 ke = *(floatx4*)&kc[n][e0];
            #pragma unroll
            for (int i = 0; i < 4; ++i)
                #pragma unroll
                for (int j = 0; j < 4; ++j)
                    acc[i][j] += qd[i] * ke[j];
        }
    }
    float* Gp = G + (sbh * 64 + d0) * 64 + e0;
    #pragma unroll
    for (int i = 0; i < 4; ++i)
        #pragma unroll
        for (int j = 0; j < 4; ++j)
            atomicAdd(&Gp[i * 64 + j], acc[i][j]);
    if (tid < 64)       atomicAdd(&NQ[sbh * 64 + tid], nacc);
    else if (tid < 128) atomicAdd(&NK[sbh * 64 + tid - 64], nacc);
}

__global__ void xca_soft(const float* __restrict__ G,
                         const float* __restrict__ NQ, const float* __restrict__ NK,
                         const float* __restrict__ misc, bf16* __restrict__ P)
{
    int sbh = blockIdx.x;
    int s = sbh >> 6;
    int h = sbh & 7;
    int d = threadIdx.x;

    __shared__ float rk[64];
    rk[d] = 1.0f / fmaxf(sqrtf(NK[sbh * 64 + d]), 1e-12f);
    __syncthreads();

    float rq = 1.0f / fmaxf(sqrtf(NQ[sbh * 64 + d]), 1e-12f);
    float t  = misc[s * 8 + h];
    const float* Gr = G + (sbh * 64 + d) * 64;

    float a[64];
    float mx = -1e30f;
    #pragma unroll
    for (int e = 0; e < 64; ++e) {
        a[e] = Gr[e] * rq * rk[e] * t;
        mx = fmaxf(mx, a[e]);
    }
    float sum = 0.f;
    #pragma unroll
    for (int e = 0; e < 64; ++e) { a[e] = expf(a[e] - mx); sum += a[e]; }
    float inv = 1.0f / sum;
    bf16* Pr = P + (sbh * 64 + d) * 64;
    #pragma unroll
    for (int e = 0; e < 64; ++e) Pr[e] = (bf16)(a[e] * inv);
}

__global__ __launch_bounds__(256) void xca_pv(
    const bf16* __restrict__ V0, const bf16* __restrict__ V1,
    const bf16* __restrict__ P, bf16* __restrict__ xca)
{
    int bid = blockIdx.x;
    int nq4 = bid & 3;
    int h   = (bid >> 2) & 7;
    int b   = (bid >> 5) & 7;
    int s   = bid >> 8;
    int sbh = s * 64 + b * 8 + h;

    const bf16* vsrc = s ? V0 : V1;

    int tid = threadIdx.x;
    int lane = tid & 63;
    int wave = tid >> 6;
    int l15 = lane & 15;
    int quad = lane >> 4;

    const bf16* Pb = P + sbh * 4096;
    bf16x8 pf[4][2];
    #pragma unroll
    for (int i = 0; i < 4; ++i)
        #pragma unroll
        for (int h2 = 0; h2 < 2; ++h2)
            pf[i][h2] = *(const bf16x8*)&Pb[(i * 16 + l15) * 64 + h2 * 32 + quad * 8];

    int n_start = nq4 * 1024 + wave * 256;
    for (int nt = 0; nt < 16; ++nt) {
        int nb = n_start + nt * 16;
        const bf16* vp = vsrc + (long)(b * NTOK + nb + l15) * CDIM + h * DH + quad * 8;
        bf16x8 v0 = *(const bf16x8*)vp;
        bf16x8 v1 = *(const bf16x8*)(vp + 32);
        floatx4 acc[4] = {};
        #pragma unroll
        for (int i = 0; i < 4; ++i) {
            acc[i] = __builtin_amdgcn_mfma_f32_16x16x32_bf16(v0, pf[i][0], acc[i], 0, 0, 0);
            acc[i] = __builtin_amdgcn_mfma_f32_16x16x32_bf16(v1, pf[i][1], acc[i], 0, 0, 0);
        }
        bf16* op = xca + (long)((s * NB + b) * NTOK + nb + quad * 4) * CDIM + h * DH + l15;
        #pragma unroll
        for (int i = 0; i < 4; ++i)
            #pragma unroll
            for (int r = 0; r < 4; ++r)
                op[(long)r * CDIM + i * 16] = (bf16)acc[i][r];
    }
}

// ws layout (bytes), total ~208.7 MB:
//   0           Q0 (33,554,432)
//   33,554,432  K0 (33,554,432)
//   67,108,864  Q1 (33,554,432)
//   100,663,296 K1 (33,554,432)
//   134,217,728 Xb0 (33,554,432)  -- bf16 cast of x;  xca overlay after QKV gemms
//   167,772,160 Xb1 (33,554,432)  -- bf16 cast of x_d
//   201,326,592 wtq0 (1,572,864)
//   202,899,456 wtq1 (1,572,864)
//   204,472,320 wtp0 (524,288)
//   204,996,608 wtp1 (524,288)
//   205,520,896 G    (2,097,152 fp32)
//   207,618,048 NQ   (32,768)
//   207,650,816 NK   (32,768)
//   207,683,584 P    (1,048,576)
//   208,732,160 flag (64)
//   208,732,224 misc (4,160)
// V0/V1 in d_out (dead scratch until the final proj overwrites it).
extern "C" void kernel_launch(void* const* d_in, const int* in_sizes, int n_in,
                              void* d_out, int out_size, void* d_ws, size_t ws_size,
                              hipStream_t stream)
{
    const void* x     = d_in[0];
    const void* x_d   = d_in[1];
    const void* Wq0   = d_in[2];
    const void* Wq1   = d_in[3];
    const void* temp0 = d_in[4];
    const void* temp1 = d_in[5];
    const void* Wp0   = d_in[6];
    const void* bp0   = d_in[7];
    const void* Wp1   = d_in[8];
    const void* bp1   = d_in[9];

    char* ws = (char*)d_ws;
    bf16*  Q0   = (bf16*)(ws);
    bf16*  K0   = (bf16*)(ws + 33554432);
    bf16*  Q1   = (bf16*)(ws + 67108864);
    bf16*  K1   = (bf16*)(ws + 100663296);
    bf16*  Xb0  = (bf16*)(ws + 134217728);
    bf16*  Xb1  = (bf16*)(ws + 167772160);
    bf16*  xca  = (bf16*)(ws + 134217728);  // overlay on Xb0+Xb1 (dead after QKV gemms)
    bf16*  wtq0 = (bf16*)(ws + 201326592);
    bf16*  wtq1 = (bf16*)(ws + 202899456);
    bf16*  wtp0 = (bf16*)(ws + 204472320);
    bf16*  wtp1 = (bf16*)(ws + 204996608);
    float* G    = (float*)(ws + 205520896);
    float* NQ   = (float*)(ws + 207618048);
    float* NK   = (float*)(ws + 207650816);
    bf16*  P    = (bf16*)(ws + 207683584);
    int*   flag = (int*)(ws + 208732160);
    float* misc = (float*)(ws + 208732224);

    bf16* V0 = (bf16*)d_out;               // V scratch in d_out (always bf16)
    bf16* V1 = (bf16*)d_out + PART_STRIDE;

    hipMemsetAsync(ws + 205520896, 0, 2162688, stream);   // zero G + NQ + NK

    detect_kernel<<<1, 256, 0, stream>>>((const bf16*)Wq0, flag);
    misc_kernel<<<1, 256, 0, stream>>>(temp0, temp1, bp0, bp1, flag, misc);

    wt_kernel<<<(512 * 1536 + 255) / 256, 256, 0, stream>>>(Wq0, wtq0, 512, 1536, flag);
    wt_kernel<<<(512 * 1536 + 255) / 256, 256, 0, stream>>>(Wq1, wtq1, 512, 1536, flag);
    wt_kernel<<<(512 * 512 + 255) / 256, 256, 0, stream>>>(Wp0, wtp0, 512, 512, flag);
    wt_kernel<<<(512 * 512 + 255) / 256, 256, 0, stream>>>(Wp1, wtp1, 512, 512, flag);

    cast_kernel<<<8192, 256, 0, stream>>>(x,   Xb0, flag);
    cast_kernel<<<8192, 256, 0, stream>>>(x_d, Xb1, flag);

    // QKV: parts 0/1 -> Q,K in ws; part 2 -> V scratch in d_out
    gemm_bt<<<dim3(256, 12), 256, 0, stream>>>(Xb0, wtq0, nullptr, Q0, V0, 0L, nullptr);
    gemm_bt<<<dim3(256, 12), 256, 0, stream>>>(Xb1, wtq1, nullptr, Q1, V1, 0L, nullptr);

    xca_gk<<<512, 256, 0, stream>>>(Q0, K0, Q1, K1, G, NQ, NK);
    xca_soft<<<128, 64, 0, stream>>>(G, NQ, NK, misc, P);
    xca_pv<<<512, 256, 0, stream>>>(V0, V1, P, xca);

    // proj GEMMs: out dtype per flag; 2nd half at element offset PART_STRIDE
    gemm_bt<<<dim3(256, 4), 256, 0, stream>>>(xca,               wtp0, misc + 16,  d_out, nullptr, 0L,          flag);
    gemm_bt<<<dim3(256, 4), 256, 0, stream>>>(xca + PART_STRIDE, wtp1, misc + 528, d_out, nullptr, PART_STRIDE, flag);
}